// Round 12
// baseline (56.151 us; speedup 1.0000x reference)
//
#include <hip/hip_runtime.h>
#include <hip/hip_bf16.h>

// NT-Xent (SimCLR) loss: B=4096, D=128, N=8192, TEMP=0.5.
// Round 12: round-8 gram geometry (2x2 quadrants, ca[4][2]=32 VGPR -- r11's
// 1x4 split spilled 23MB/dispatch) + the register-neutral VALU cuts:
//   (a) cached side loads pre-scaled znK -> epilogue e = exp2f(acc), no mul;
//   (b) self-tile in its own y=0 partition -> jp += e unconditional;
//   (c) finalize fused into the LAST gram block via done-counter with NO
//       __threadfence (r7 lesson: per-block L2-writeback fences serialize
//       chip-wide). Protocol: per-wave s_waitcnt vmcnt(0) -> syncthreads ->
//       relaxed device-scope fetch_add; last block reads sumexp with
//       device-scope atomic loads (all updates were device-scope atomics).

typedef short bfrag __attribute__((ext_vector_type(8)));   // 8 bf16 (4 VGPRs)
typedef float f32x4 __attribute__((ext_vector_type(4)));

static __device__ __forceinline__ unsigned short f2bf_rne(float x) {
    unsigned u = __float_as_uint(x);
    return (unsigned short)((u + 0x7fffu + ((u >> 16) & 1u)) >> 16);
}
static __device__ __forceinline__ float bf2f(unsigned short b) {
    return __uint_as_float(((unsigned)b) << 16);
}

// ------ kernel 1: normalize pair (i, i+B); emit zn (unit bf16) and
// znK (bf16 of K_E*unit); diag = dot(znK, zn) pre-scaled; pos; zero
// sumexp and done.
__global__ __launch_bounds__(256) void nt_norm_pair(
        const float* __restrict__ zi, const float* __restrict__ zj,
        unsigned short* __restrict__ zn, unsigned short* __restrict__ znK,
        float* __restrict__ diag, float* __restrict__ pos,
        float* __restrict__ sumexp, int* __restrict__ done) {
    constexpr int B = 4096, D = 128;
    constexpr float K_E = 2.8853900817779268f;             // 2 * log2(e)
    const int wave = threadIdx.x >> 6, lane = threadIdx.x & 63;
    const int p = blockIdx.x * 4 + wave;                   // 0..4095
    float2 a = reinterpret_cast<const float2*>(zi + (size_t)p * D)[lane];
    float2 b = reinterpret_cast<const float2*>(zj + (size_t)p * D)[lane];
    float sa = a.x * a.x + a.y * a.y;
    float sb = b.x * b.x + b.y * b.y;
    #pragma unroll
    for (int m = 32; m; m >>= 1) { sa += __shfl_xor(sa, m); sb += __shfl_xor(sb, m); }
    float ia = 1.f / fmaxf(sqrtf(sa), 1e-8f);
    float ib = 1.f / fmaxf(sqrtf(sb), 1e-8f);
    unsigned short a0 = f2bf_rne(a.x * ia), a1 = f2bf_rne(a.y * ia);
    unsigned short b0 = f2bf_rne(b.x * ib), b1 = f2bf_rne(b.y * ib);
    float fa0 = bf2f(a0), fa1 = bf2f(a1), fb0 = bf2f(b0), fb1 = bf2f(b1);
    unsigned short aK0 = f2bf_rne(K_E * fa0), aK1 = f2bf_rne(K_E * fa1);
    unsigned short bK0 = f2bf_rne(K_E * fb0), bK1 = f2bf_rne(K_E * fb1);
    float da = bf2f(aK0) * fa0 + bf2f(aK1) * fa1;          // pre-scaled self-dot
    float db = bf2f(bK0) * fb0 + bf2f(bK1) * fb1;
    float cr = fa0 * fb0 + fa1 * fb1;                      // unit cross-dot
    #pragma unroll
    for (int m = 32; m; m >>= 1) {
        da += __shfl_xor(da, m); db += __shfl_xor(db, m); cr += __shfl_xor(cr, m);
    }
    reinterpret_cast<unsigned*>(zn  + (size_t)p * D)[lane] =
        (unsigned)a0 | ((unsigned)a1 << 16);
    reinterpret_cast<unsigned*>(zn  + (size_t)(p + B) * D)[lane] =
        (unsigned)b0 | ((unsigned)b1 << 16);
    reinterpret_cast<unsigned*>(znK + (size_t)p * D)[lane] =
        (unsigned)aK0 | ((unsigned)aK1 << 16);
    reinterpret_cast<unsigned*>(znK + (size_t)(p + B) * D)[lane] =
        (unsigned)bK0 | ((unsigned)bK1 << 16);
    if (lane == 0) {
        diag[p] = da; diag[p + B] = db;
        pos[p] = 2.f * cr; pos[p + B] = 2.f * cr;          // sim symmetric
        sumexp[p] = 0.f; sumexp[p + B] = 0.f;              // replaces hipMemsetAsync
    }
    if (blockIdx.x == 0 && threadIdx.x == 0) *done = 0;
}

// ------ kernel 2: strip-mined symmetric gram + fused last-block finalize ---
// grid (128, 17): cached tile c = blockIdx.x.
//   y == 0   : self-tile d=0 only (T=1; jp never flushed).
//   y = 1..16: T=4 strip, d = 4(y-1)+1 .. 4(y-1)+4 (d in 1..64);
//              d=64 (y==16,t==3) only for c<64 -> T=3 for c>=64.
// All 2176 blocks active; each unordered 64-tile pair exactly once.
#define NACTIVE 2176
__global__ __launch_bounds__(256, 4) void nt_gram_sym(
        const unsigned short* __restrict__ zn,
        const unsigned short* __restrict__ znK,
        float* __restrict__ sumexp, const float* __restrict__ diag,
        const float* __restrict__ pos, int* __restrict__ done,
        float* __restrict__ out) {
    const int c = blockIdx.x;
    const int y = blockIdx.y;
    const int T  = (y == 0) ? 1 : ((y == 16 && c >= 64) ? 3 : 4);
    const int d0 = (y == 0) ? 0 : 4 * (y - 1) + 1;

    __shared__ short buf[2][64][128];                      // 2 x 16 KB stream buffers
    __shared__ float red[4];
    __shared__ int lastFlag;

    const short* zs  = (const short*)zn;
    const short* zsK = (const short*)znK;
    const int tid = threadIdx.x, wid = tid >> 6, lane = tid & 63;
    const int wj = wid >> 1, wi = wid & 1;                 // wave quadrant
    const int lr = lane & 15, lk = lane >> 4;

    // cached A-frags (tile c, this wave's 32 j-rows) from znK (pre-scaled)
    bfrag ca[4][2];
    {
        const int rbase = c * 64 + wj * 32;
        #pragma unroll
        for (int ks = 0; ks < 4; ++ks)
            #pragma unroll
            for (int f = 0; f < 2; ++f)
                ca[ks][f] = *reinterpret_cast<const bfrag*>(
                    zsK + (size_t)(rbase + f * 16 + lr) * 128 + ks * 32 + lk * 8);
    }
    asm volatile("s_waitcnt vmcnt(0)" ::: "memory");       // drain ca: clean vmcnt base

    // stage streamed tile t into buf[slot]: 1024 x 16B chunks, 4 per thread.
    // LDS linear; global source pre-swizzled: LDS (r, cpos) holds chunk cpos^(r&7).
    auto STAGE = [&](int t, int slot) {
        const int srow = ((c + d0 + t) & 127) * 64;
        #pragma unroll
        for (int q = 0; q < 4; ++q) {
            const int cbase = q * 256 + wid * 64;          // wave-uniform
            const int chunk = cbase + lane;                // 0..1023
            const int r = chunk >> 4;
            const int cpos = chunk & 15;
            const int csrc = cpos ^ (r & 7);
            const short* g = zs + (size_t)(srow + r) * 128 + csrc * 8;
            __builtin_amdgcn_global_load_lds(
                (const __attribute__((address_space(1))) void*)g,
                (__attribute__((address_space(3))) void*)(
                    &buf[slot][0][0] + (size_t)cbase * 8),
                16, 0, 0);
        }
    };

    STAGE(0, 0);

    float jp[8] = {0.f, 0.f, 0.f, 0.f, 0.f, 0.f, 0.f, 0.f};

    for (int t = 0; t < T; ++t) {
        const bool more = (t + 1 < T);
        if (more) STAGE(t + 1, (t + 1) & 1);
        // Counted waits: STAGE(t) done; prior tile's 2 epilogue atomics +
        // STAGE(t+1)'s 4 loads stay in flight.
        if (t == 0) {
            if (more) asm volatile("s_waitcnt vmcnt(4)" ::: "memory");
            else      asm volatile("s_waitcnt vmcnt(0)" ::: "memory");
        } else {
            if (more) asm volatile("s_waitcnt vmcnt(6)" ::: "memory");
            else      asm volatile("s_waitcnt vmcnt(2)" ::: "memory");
        }
        __builtin_amdgcn_s_barrier();

        // ---- compute tile t from buf[t&1] ----
        const int sb = ((c + d0 + t) & 127) * 64;          // streamed base row (i side)
        f32x4 acc[2][2] = {};                              // [fj][fi]
        #pragma unroll
        for (int ks = 0; ks < 4; ++ks) {
            bfrag cb[2];
            #pragma unroll
            for (int f = 0; f < 2; ++f) {
                const int r = wi * 32 + f * 16 + lr;
                const int cc = (ks * 4 + lk) ^ (lr & 7);   // swizzled chunk index
                cb[f] = *reinterpret_cast<const bfrag*>(&buf[t & 1][r][cc * 8]);
            }
            #pragma unroll
            for (int fj = 0; fj < 2; ++fj)
                #pragma unroll
                for (int fi = 0; fi < 2; ++fi)
                    acc[fj][fi] = __builtin_amdgcn_mfma_f32_16x16x32_bf16(
                        ca[ks][fj], cb[fi], acc[fj][fi], 0, 0, 0);
        }

        // epilogue: acc already = K_E * sim -> e = exp2(acc); jp += e always
        // (self-tile lives only in y==0 blocks, which never flush jp).
        #pragma unroll
        for (int fi = 0; fi < 2; ++fi) {
            float s = 0.f;
            #pragma unroll
            for (int fj = 0; fj < 2; ++fj)
                #pragma unroll
                for (int r = 0; r < 4; ++r) {
                    const float e = exp2f(acc[fj][fi][r]);
                    s += e;
                    jp[fj * 4 + r] += e;
                }
            s += __shfl_xor(s, 16);                        // i-row sum over lk groups
            s += __shfl_xor(s, 32);
            if (lk == 0) atomicAdd(&sumexp[sb + wi * 32 + fi * 16 + lr], s);
        }
        __builtin_amdgcn_s_barrier();                      // all waves done with buf[t&1]
    }

    // ---- once per block (y>=1): reduce j-col partials over 16 lr lanes ----
    if (y != 0) {
        float myv = 0.f;
        #pragma unroll
        for (int tt = 0; tt < 8; ++tt) {
            float v = jp[tt];
            v += __shfl_xor(v, 1);
            v += __shfl_xor(v, 2);
            v += __shfl_xor(v, 4);
            v += __shfl_xor(v, 8);
            if (lr == tt) myv = v;                         // designated writer
        }
        if (lr < 8)
            atomicAdd(&sumexp[c * 64 + wj * 32 + (lr >> 2) * 16 + lk * 4 + (lr & 3)],
                      myv);
    }

    // ---- fused finalize: done-counter, NO threadfence ----
    asm volatile("s_waitcnt vmcnt(0)" ::: "memory");       // my atomics ACKed (per wave)
    __syncthreads();                                       // all 4 waves drained
    if (tid == 0) {
        int v = __hip_atomic_fetch_add(done, 1, __ATOMIC_RELAXED,
                                       __HIP_MEMORY_SCOPE_AGENT);
        lastFlag = (v == NACTIVE - 1);
    }
    __syncthreads();
    if (!lastFlag) return;

    constexpr int N = 8192;
    float s = 0.f;
    for (int i = tid; i < N; i += 256) {
        float se = __hip_atomic_load(&sumexp[i], __ATOMIC_RELAXED,
                                     __HIP_MEMORY_SCOPE_AGENT);
        s += __logf(se - exp2f(diag[i])) - pos[i];         // diag pre-scaled
    }
    #pragma unroll
    for (int m = 32; m; m >>= 1) s += __shfl_xor(s, m);
    if (lane == 0) red[wid] = s;
    __syncthreads();
    if (tid == 0)
        out[0] = (red[0] + red[1] + red[2] + red[3]) * (1.0f / (float)N);
}

extern "C" void kernel_launch(void* const* d_in, const int* in_sizes, int n_in,
                              void* d_out, int out_size, void* d_ws, size_t ws_size,
                              hipStream_t stream) {
    const float* zi = (const float*)d_in[0];
    const float* zj = (const float*)d_in[1];
    float* out = (float*)d_out;

    char* ws = (char*)d_ws;
    unsigned short* zn  = (unsigned short*)ws;                     // 2 MB
    unsigned short* znK = (unsigned short*)(ws + 2 * 1024 * 1024); // 2 MB
    float* sumexp = (float*)(ws + 4 * 1024 * 1024);                // 32 KB
    float* diag   = (float*)(ws + 4 * 1024 * 1024 + 1 * 32768);    // 32 KB
    float* pos    = (float*)(ws + 4 * 1024 * 1024 + 2 * 32768);    // 32 KB
    int*   done   = (int*)  (ws + 4 * 1024 * 1024 + 3 * 32768);    // 4 B

    nt_norm_pair<<<1024, 256, 0, stream>>>(zi, zj, zn, znK, diag, pos, sumexp, done);
    nt_gram_sym<<<dim3(128, 17), 256, 0, stream>>>(zn, znK, sumexp, diag, pos, done, out);
}

// Round 13
// 42.750 us; speedup vs baseline: 1.3135x; 1.3135x over previous
//
#include <hip/hip_runtime.h>
#include <hip/hip_bf16.h>

// NT-Xent (SimCLR) loss: B=4096, D=128, N=8192, TEMP=0.5.
// Round 13: round-8 structure EXACTLY (3 kernels, fire-and-forget atomics --
// fusion refuted twice: r7 fence=113us, r12 counter=56us) + isolated VALU
// cuts: (a) znK = bf16(2*log2(e)*zhat) cached operand -> e = exp2f(acc)
// directly; (b) self-tile in y=0 partition -> jp += e unconditional;
// (c) launch_bounds(256,5): 5 blocks/CU at exactly 32KB LDS.

typedef short bfrag __attribute__((ext_vector_type(8)));   // 8 bf16 (4 VGPRs)
typedef float f32x4 __attribute__((ext_vector_type(4)));

static __device__ __forceinline__ unsigned short f2bf_rne(float x) {
    unsigned u = __float_as_uint(x);
    return (unsigned short)((u + 0x7fffu + ((u >> 16) & 1u)) >> 16);
}
static __device__ __forceinline__ float bf2f(unsigned short b) {
    return __uint_as_float(((unsigned)b) << 16);
}

// ------ kernel 1: normalize pair (i, i+B); emit zn (unit bf16) and
// znK (bf16 of K_E*unit); diag = dot(znK_bf16, zn_bf16) (matches the MFMA
// self-entry); pos; zero sumexp.
__global__ __launch_bounds__(256) void nt_norm_pair(
        const float* __restrict__ zi, const float* __restrict__ zj,
        unsigned short* __restrict__ zn, unsigned short* __restrict__ znK,
        float* __restrict__ diag, float* __restrict__ pos,
        float* __restrict__ sumexp) {
    constexpr int B = 4096, D = 128;
    constexpr float K_E = 2.8853900817779268f;             // 2 * log2(e)
    const int wave = threadIdx.x >> 6, lane = threadIdx.x & 63;
    const int p = blockIdx.x * 4 + wave;                   // 0..4095
    float2 a = reinterpret_cast<const float2*>(zi + (size_t)p * D)[lane];
    float2 b = reinterpret_cast<const float2*>(zj + (size_t)p * D)[lane];
    float sa = a.x * a.x + a.y * a.y;
    float sb = b.x * b.x + b.y * b.y;
    #pragma unroll
    for (int m = 32; m; m >>= 1) { sa += __shfl_xor(sa, m); sb += __shfl_xor(sb, m); }
    float ia = 1.f / fmaxf(sqrtf(sa), 1e-8f);
    float ib = 1.f / fmaxf(sqrtf(sb), 1e-8f);
    unsigned short a0 = f2bf_rne(a.x * ia), a1 = f2bf_rne(a.y * ia);
    unsigned short b0 = f2bf_rne(b.x * ib), b1 = f2bf_rne(b.y * ib);
    float fa0 = bf2f(a0), fa1 = bf2f(a1), fb0 = bf2f(b0), fb1 = bf2f(b1);
    unsigned short aK0 = f2bf_rne(K_E * fa0), aK1 = f2bf_rne(K_E * fa1);
    unsigned short bK0 = f2bf_rne(K_E * fb0), bK1 = f2bf_rne(K_E * fb1);
    float da = bf2f(aK0) * fa0 + bf2f(aK1) * fa1;          // pre-scaled self-dot
    float db = bf2f(bK0) * fb0 + bf2f(bK1) * fb1;
    float cr = fa0 * fb0 + fa1 * fb1;                      // unit cross-dot
    #pragma unroll
    for (int m = 32; m; m >>= 1) {
        da += __shfl_xor(da, m); db += __shfl_xor(db, m); cr += __shfl_xor(cr, m);
    }
    reinterpret_cast<unsigned*>(zn  + (size_t)p * D)[lane] =
        (unsigned)a0 | ((unsigned)a1 << 16);
    reinterpret_cast<unsigned*>(zn  + (size_t)(p + B) * D)[lane] =
        (unsigned)b0 | ((unsigned)b1 << 16);
    reinterpret_cast<unsigned*>(znK + (size_t)p * D)[lane] =
        (unsigned)aK0 | ((unsigned)aK1 << 16);
    reinterpret_cast<unsigned*>(znK + (size_t)(p + B) * D)[lane] =
        (unsigned)bK0 | ((unsigned)bK1 << 16);
    if (lane == 0) {
        diag[p] = da; diag[p + B] = db;
        pos[p] = 2.f * cr; pos[p + B] = 2.f * cr;          // sim symmetric
        sumexp[p] = 0.f; sumexp[p + B] = 0.f;              // replaces hipMemsetAsync
    }
}

// ------ kernel 2: strip-mined symmetric gram ------------------------------
// grid (128, 17): cached tile c = blockIdx.x.
//   y == 0   : self-tile d=0 only (T=1; jp never flushed).
//   y = 1..16: T=4 strip, d = 4(y-1)+1 .. 4(y-1)+4 (d in 1..64);
//              d=64 (y==16,t==3) only valid for c<64 -> T=3 for c>=64.
// Each unordered 64-tile pair exactly once (8256 tile-computes).
// acc[fj][fi] = K_E * sim[j in cached c][i in streamed].
__global__ __launch_bounds__(256, 5) void nt_gram_sym(
        const unsigned short* __restrict__ zn,
        const unsigned short* __restrict__ znK,
        float* __restrict__ sumexp) {
    const int c = blockIdx.x;
    const int y = blockIdx.y;
    const int T  = (y == 0) ? 1 : ((y == 16 && c >= 64) ? 3 : 4);
    const int d0 = (y == 0) ? 0 : 4 * (y - 1) + 1;

    __shared__ short buf[2][64][128];                      // 2 x 16 KB stream buffers

    const short* zs  = (const short*)zn;
    const short* zsK = (const short*)znK;
    const int tid = threadIdx.x, wid = tid >> 6, lane = tid & 63;
    const int wj = wid >> 1, wi = wid & 1;                 // wave quadrant
    const int lr = lane & 15, lk = lane >> 4;

    // cached A-frags (tile c, this wave's 32 j-rows) from znK (pre-scaled)
    bfrag ca[4][2];
    {
        const int rbase = c * 64 + wj * 32;
        #pragma unroll
        for (int ks = 0; ks < 4; ++ks)
            #pragma unroll
            for (int f = 0; f < 2; ++f)
                ca[ks][f] = *reinterpret_cast<const bfrag*>(
                    zsK + (size_t)(rbase + f * 16 + lr) * 128 + ks * 32 + lk * 8);
    }
    asm volatile("s_waitcnt vmcnt(0)" ::: "memory");       // drain ca: clean vmcnt base

    // stage streamed tile t into buf[slot]: 1024 x 16B chunks, 4 per thread.
    // LDS linear; global source pre-swizzled: LDS (r, cpos) holds chunk cpos^(r&7).
    auto STAGE = [&](int t, int slot) {
        const int srow = ((c + d0 + t) & 127) * 64;
        #pragma unroll
        for (int q = 0; q < 4; ++q) {
            const int cbase = q * 256 + wid * 64;          // wave-uniform
            const int chunk = cbase + lane;                // 0..1023
            const int r = chunk >> 4;
            const int cpos = chunk & 15;
            const int csrc = cpos ^ (r & 7);
            const short* g = zs + (size_t)(srow + r) * 128 + csrc * 8;
            __builtin_amdgcn_global_load_lds(
                (const __attribute__((address_space(1))) void*)g,
                (__attribute__((address_space(3))) void*)(
                    &buf[slot][0][0] + (size_t)cbase * 8),
                16, 0, 0);
        }
    };

    STAGE(0, 0);

    float jp[8] = {0.f, 0.f, 0.f, 0.f, 0.f, 0.f, 0.f, 0.f};

    for (int t = 0; t < T; ++t) {
        const bool more = (t + 1 < T);
        if (more) STAGE(t + 1, (t + 1) & 1);
        // Counted waits: STAGE(t) done; prior tile's 2 epilogue atomics +
        // STAGE(t+1)'s 4 loads stay in flight.
        if (t == 0) {
            if (more) asm volatile("s_waitcnt vmcnt(4)" ::: "memory");
            else      asm volatile("s_waitcnt vmcnt(0)" ::: "memory");
        } else {
            if (more) asm volatile("s_waitcnt vmcnt(6)" ::: "memory");
            else      asm volatile("s_waitcnt vmcnt(2)" ::: "memory");
        }
        __builtin_amdgcn_s_barrier();

        // ---- compute tile t from buf[t&1] ----
        const int sb = ((c + d0 + t) & 127) * 64;          // streamed base row (i side)
        f32x4 acc[2][2] = {};                              // [fj][fi]
        #pragma unroll
        for (int ks = 0; ks < 4; ++ks) {
            bfrag cb[2];
            #pragma unroll
            for (int f = 0; f < 2; ++f) {
                const int r = wi * 32 + f * 16 + lr;
                const int cc = (ks * 4 + lk) ^ (lr & 7);   // swizzled chunk index
                cb[f] = *reinterpret_cast<const bfrag*>(&buf[t & 1][r][cc * 8]);
            }
            #pragma unroll
            for (int fj = 0; fj < 2; ++fj)
                #pragma unroll
                for (int fi = 0; fi < 2; ++fi)
                    acc[fj][fi] = __builtin_amdgcn_mfma_f32_16x16x32_bf16(
                        ca[ks][fj], cb[fi], acc[fj][fi], 0, 0, 0);
        }

        // epilogue: acc already = K_E * sim -> e = exp2(acc); jp += e always
        // (self-tile lives only in y==0 blocks, which never flush jp).
        #pragma unroll
        for (int fi = 0; fi < 2; ++fi) {
            float s = 0.f;
            #pragma unroll
            for (int fj = 0; fj < 2; ++fj)
                #pragma unroll
                for (int r = 0; r < 4; ++r) {
                    const float e = exp2f(acc[fj][fi][r]);
                    s += e;
                    jp[fj * 4 + r] += e;
                }
            s += __shfl_xor(s, 16);                        // i-row sum over lk groups
            s += __shfl_xor(s, 32);
            if (lk == 0) atomicAdd(&sumexp[sb + wi * 32 + fi * 16 + lr], s);
        }
        __builtin_amdgcn_s_barrier();                      // all waves done with buf[t&1]
    }

    // ---- once per block (y>=1): reduce j-col partials over 16 lr lanes ----
    if (y != 0) {
        float myv = 0.f;
        #pragma unroll
        for (int tt = 0; tt < 8; ++tt) {
            float v = jp[tt];
            v += __shfl_xor(v, 1);
            v += __shfl_xor(v, 2);
            v += __shfl_xor(v, 4);
            v += __shfl_xor(v, 8);
            if (lr == tt) myv = v;                         // designated writer
        }
        if (lr < 8)
            atomicAdd(&sumexp[c * 64 + wj * 32 + (lr >> 2) * 16 + lk * 4 + (lr & 3)],
                      myv);
    }
}

// ------ kernel 3: finalize scalar ------------------------------------------
__global__ __launch_bounds__(1024) void nt_finalize(
        const float* __restrict__ sumexp, const float* __restrict__ diag,
        const float* __restrict__ pos, float* __restrict__ out) {
    constexpr int N = 8192;
    float s = 0.f;
    for (int i = threadIdx.x; i < N; i += 1024)
        s += __logf(sumexp[i] - exp2f(diag[i])) - pos[i];  // diag pre-scaled
    #pragma unroll
    for (int m = 32; m; m >>= 1) s += __shfl_xor(s, m);
    __shared__ float red[16];
    if ((threadIdx.x & 63) == 0) red[threadIdx.x >> 6] = s;
    __syncthreads();
    if (threadIdx.x == 0) {
        float t = 0.f;
        #pragma unroll
        for (int w = 0; w < 16; ++w) t += red[w];
        out[0] = t * (1.0f / (float)N);
    }
}

extern "C" void kernel_launch(void* const* d_in, const int* in_sizes, int n_in,
                              void* d_out, int out_size, void* d_ws, size_t ws_size,
                              hipStream_t stream) {
    const float* zi = (const float*)d_in[0];
    const float* zj = (const float*)d_in[1];
    float* out = (float*)d_out;

    char* ws = (char*)d_ws;
    unsigned short* zn  = (unsigned short*)ws;                     // 2 MB
    unsigned short* znK = (unsigned short*)(ws + 2 * 1024 * 1024); // 2 MB
    float* sumexp = (float*)(ws + 4 * 1024 * 1024);                // 32 KB
    float* diag   = (float*)(ws + 4 * 1024 * 1024 + 1 * 32768);    // 32 KB
    float* pos    = (float*)(ws + 4 * 1024 * 1024 + 2 * 32768);    // 32 KB

    nt_norm_pair<<<1024, 256, 0, stream>>>(zi, zj, zn, znK, diag, pos, sumexp);
    nt_gram_sym<<<dim3(128, 17), 256, 0, stream>>>(zn, znK, sumexp);
    nt_finalize<<<1, 1024, 0, stream>>>(sumexp, diag, pos, out);
}

// Round 14
// 35.886 us; speedup vs baseline: 1.5647x; 1.1913x over previous
//
#include <hip/hip_runtime.h>
#include <hip/hip_bf16.h>

// NT-Xent (SimCLR) loss: B=4096, D=128, N=8192, TEMP=0.5.
// Round 14: exact round-8 structure (best: 36.0us, twice reproduced) with
// ONE mechanism change: single-barrier pipelined loop.
//   - STAGE(t+1) issued AFTER the leading barrier (not before the wait):
//     the barrier already proves all waves finished reading buf[(t+1)&1]
//     in iter t-1, so the trailing barrier is deleted (2 -> 1 barriers/tile)
//     and the stage's L2 latency hides under a full tile of compute.
//   - steady-state wait is vmcnt(2) (2 newest = prior iter's atomics;
//     vmcnt counts in-order per m135, so stage(t) is provably complete).
//   - prologue: STAGE(0) issued before the ca register loads; the t==0
//     vmcnt(0) drains both (one serial drain instead of two).
// Everything else (geometry, cw self-tile weight, atomics, finalize) = r8.

typedef short bfrag __attribute__((ext_vector_type(8)));   // 8 bf16 (4 VGPRs)
typedef float f32x4 __attribute__((ext_vector_type(4)));

static __device__ __forceinline__ unsigned short f2bf_rne(float x) {
    unsigned u = __float_as_uint(x);
    return (unsigned short)((u + 0x7fffu + ((u >> 16) & 1u)) >> 16);
}
static __device__ __forceinline__ float bf2f(unsigned short b) {
    return __uint_as_float(((unsigned)b) << 16);
}

// ------ kernel 1: normalize pair (i, i+B); emit zn/bf16, diag, pos; zero sumexp
__global__ __launch_bounds__(256) void nt_norm_pair(
        const float* __restrict__ zi, const float* __restrict__ zj,
        unsigned short* __restrict__ zn, float* __restrict__ diag,
        float* __restrict__ pos, float* __restrict__ sumexp) {
    constexpr int B = 4096, D = 128;
    const int wave = threadIdx.x >> 6, lane = threadIdx.x & 63;
    const int p = blockIdx.x * 4 + wave;                   // 0..4095
    float2 a = reinterpret_cast<const float2*>(zi + (size_t)p * D)[lane];
    float2 b = reinterpret_cast<const float2*>(zj + (size_t)p * D)[lane];
    float sa = a.x * a.x + a.y * a.y;
    float sb = b.x * b.x + b.y * b.y;
    #pragma unroll
    for (int m = 32; m; m >>= 1) { sa += __shfl_xor(sa, m); sb += __shfl_xor(sb, m); }
    float ia = 1.f / fmaxf(sqrtf(sa), 1e-8f);
    float ib = 1.f / fmaxf(sqrtf(sb), 1e-8f);
    unsigned short a0 = f2bf_rne(a.x * ia), a1 = f2bf_rne(a.y * ia);
    unsigned short b0 = f2bf_rne(b.x * ib), b1 = f2bf_rne(b.y * ib);
    float fa0 = bf2f(a0), fa1 = bf2f(a1), fb0 = bf2f(b0), fb1 = bf2f(b1);
    float da = fa0 * fa0 + fa1 * fa1;                      // bf16 self-dot (matches MFMA diag)
    float db = fb0 * fb0 + fb1 * fb1;
    float cr = fa0 * fb0 + fa1 * fb1;                      // bf16 cross-dot (positive pair)
    #pragma unroll
    for (int m = 32; m; m >>= 1) {
        da += __shfl_xor(da, m); db += __shfl_xor(db, m); cr += __shfl_xor(cr, m);
    }
    reinterpret_cast<unsigned*>(zn + (size_t)p * D)[lane] =
        (unsigned)a0 | ((unsigned)a1 << 16);
    reinterpret_cast<unsigned*>(zn + (size_t)(p + B) * D)[lane] =
        (unsigned)b0 | ((unsigned)b1 << 16);
    if (lane == 0) {
        diag[p] = da; diag[p + B] = db;
        pos[p] = 2.f * cr; pos[p + B] = 2.f * cr;          // sim symmetric
        sumexp[p] = 0.f; sumexp[p + B] = 0.f;              // replaces hipMemsetAsync
    }
}

// ------ kernel 2: strip-mined symmetric gram, single-barrier pipeline ------
// grid (128, 17): cached tile c = blockIdx.x; y<16: streamed tiles at
// d = 4y+t (t=0..3); y==16 (c<64 only): single tile d=64. Each unordered
// tile pair exactly once. acc[fj][fi] = sim[j in cached][i in streamed].
__global__ __launch_bounds__(256, 4) void nt_gram_sym(
        const unsigned short* __restrict__ zn, float* __restrict__ sumexp) {
    const int c = blockIdx.x;
    const int y = blockIdx.y;
    if (y == 16 && c >= 64) return;
    const int T  = (y == 16) ? 1 : 4;
    const int d0 = (y == 16) ? 64 : 4 * y;

    __shared__ short buf[2][64][128];                      // 2 x 16 KB stream buffers

    const short* zs = (const short*)zn;
    const int tid = threadIdx.x, wid = tid >> 6, lane = tid & 63;
    const int wj = wid >> 1, wi = wid & 1;                 // wave quadrant
    const int lr = lane & 15, lk = lane >> 4;

    // stage streamed tile t into buf[slot]: 1024 x 16B chunks, 4 per thread.
    // LDS linear; global source pre-swizzled: LDS (r, cpos) holds chunk cpos^(r&7).
    auto STAGE = [&](int t, int slot) {
        const int srow = ((c + d0 + t) & 127) * 64;
        #pragma unroll
        for (int q = 0; q < 4; ++q) {
            const int cbase = q * 256 + wid * 64;          // wave-uniform
            const int chunk = cbase + lane;                // 0..1023
            const int r = chunk >> 4;
            const int cpos = chunk & 15;
            const int csrc = cpos ^ (r & 7);
            const short* g = zs + (size_t)(srow + r) * 128 + csrc * 8;
            __builtin_amdgcn_global_load_lds(
                (const __attribute__((address_space(1))) void*)g,
                (__attribute__((address_space(3))) void*)(
                    &buf[slot][0][0] + (size_t)cbase * 8),
                16, 0, 0);
        }
    };

    STAGE(0, 0);                                           // earliest possible issue

    // cached A-frags (tile c, this wave's 32 j-rows), direct from L2 --
    // issued after STAGE(0) so the t==0 vmcnt(0) drains both together.
    bfrag ca[4][2];
    {
        const int rbase = c * 64 + wj * 32;
        #pragma unroll
        for (int ks = 0; ks < 4; ++ks)
            #pragma unroll
            for (int f = 0; f < 2; ++f)
                ca[ks][f] = *reinterpret_cast<const bfrag*>(
                    zs + (size_t)(rbase + f * 16 + lr) * 128 + ks * 32 + lk * 8);
    }

    constexpr float K_E = 2.8853900817779268f;             // 2 * log2(e)
    float jp[8] = {0.f, 0.f, 0.f, 0.f, 0.f, 0.f, 0.f, 0.f};

    for (int t = 0; t < T; ++t) {
        // wait: stage(t) complete for THIS wave. t==0 also drains ca.
        // t>=1: queue oldest->newest = [atomics(t-2)]2 [stage(t)]4
        // [atomics(t-1)]2 -> vmcnt(2) leaves only the 2 newest atomics
        // (vmcnt retires in issue order, m135).
        if (t == 0) asm volatile("s_waitcnt vmcnt(0)" ::: "memory");
        else        asm volatile("s_waitcnt vmcnt(2)" ::: "memory");
        // single barrier: all waves have stage(t) visible AND have finished
        // computing tile t-1 -> safe to overwrite buf[(t+1)&1] below.
        __builtin_amdgcn_s_barrier();
        if (t + 1 < T) STAGE(t + 1, (t + 1) & 1);          // hides under compute(t)

        // ---- compute tile t from buf[t&1] ----
        const int sb = ((c + d0 + t) & 127) * 64;          // streamed base row (i side)
        f32x4 acc[2][2] = {};                              // [fj][fi]
        #pragma unroll
        for (int ks = 0; ks < 4; ++ks) {
            bfrag cb[2];
            #pragma unroll
            for (int f = 0; f < 2; ++f) {
                const int r = wi * 32 + f * 16 + lr;
                const int cc = (ks * 4 + lk) ^ (lr & 7);   // swizzled chunk index
                cb[f] = *reinterpret_cast<const bfrag*>(&buf[t & 1][r][cc * 8]);
            }
            #pragma unroll
            for (int fj = 0; fj < 2; ++fj)
                #pragma unroll
                for (int fi = 0; fi < 2; ++fi)
                    acc[fj][fi] = __builtin_amdgcn_mfma_f32_16x16x32_bf16(
                        ca[ks][fj], cb[fi], acc[fj][fi], 0, 0, 0);
        }

        const float cw = (d0 + t) ? 1.f : 0.f;             // self-tile: no col weight
        #pragma unroll
        for (int fi = 0; fi < 2; ++fi) {
            float s = 0.f;
            #pragma unroll
            for (int fj = 0; fj < 2; ++fj)
                #pragma unroll
                for (int r = 0; r < 4; ++r) {
                    const float e = exp2f(acc[fj][fi][r] * K_E);
                    s += e;
                    jp[fj * 4 + r] += e * cw;              // j-col partial (reg, whole strip)
                }
            s += __shfl_xor(s, 16);                        // i-row sum over lk groups
            s += __shfl_xor(s, 32);
            if (lk == 0) atomicAdd(&sumexp[sb + wi * 32 + fi * 16 + lr], s);
        }
        // no trailing barrier: next iteration's leading barrier protects buf.
    }

    // ---- once per block: reduce j-col partials over 16 lr lanes ----
    float myv = 0.f;
    #pragma unroll
    for (int tt = 0; tt < 8; ++tt) {
        float v = jp[tt];
        v += __shfl_xor(v, 1);
        v += __shfl_xor(v, 2);
        v += __shfl_xor(v, 4);
        v += __shfl_xor(v, 8);
        if (lr == tt) myv = v;                             // designated writer
    }
    if (lr < 8)
        atomicAdd(&sumexp[c * 64 + wj * 32 + (lr >> 2) * 16 + lk * 4 + (lr & 3)], myv);
}

// ------ kernel 3: finalize scalar ------------------------------------------
__global__ __launch_bounds__(1024) void nt_finalize(
        const float* __restrict__ sumexp, const float* __restrict__ diag,
        const float* __restrict__ pos, float* __restrict__ out) {
    constexpr int N = 8192;
    constexpr float K_E = 2.8853900817779268f;
    float s = 0.f;
    for (int i = threadIdx.x; i < N; i += 1024)
        s += __logf(sumexp[i] - exp2f(diag[i] * K_E)) - pos[i];
    #pragma unroll
    for (int m = 32; m; m >>= 1) s += __shfl_xor(s, m);
    __shared__ float red[16];
    if ((threadIdx.x & 63) == 0) red[threadIdx.x >> 6] = s;
    __syncthreads();
    if (threadIdx.x == 0) {
        float t = 0.f;
        #pragma unroll
        for (int w = 0; w < 16; ++w) t += red[w];
        out[0] = t * (1.0f / (float)N);
    }
}

extern "C" void kernel_launch(void* const* d_in, const int* in_sizes, int n_in,
                              void* d_out, int out_size, void* d_ws, size_t ws_size,
                              hipStream_t stream) {
    const float* zi = (const float*)d_in[0];
    const float* zj = (const float*)d_in[1];
    float* out = (float*)d_out;

    char* ws = (char*)d_ws;
    unsigned short* zn = (unsigned short*)ws;                    // 2 MB
    float* sumexp = (float*)(ws + 2 * 1024 * 1024);              // 32 KB
    float* diag   = (float*)(ws + 2 * 1024 * 1024 + 1 * 32768);  // 32 KB
    float* pos    = (float*)(ws + 2 * 1024 * 1024 + 2 * 32768);  // 32 KB

    nt_norm_pair<<<1024, 256, 0, stream>>>(zi, zj, zn, diag, pos, sumexp);
    nt_gram_sym<<<dim3(128, 17), 256, 0, stream>>>(zn, sumexp);
    nt_finalize<<<1, 1024, 0, stream>>>(sumexp, diag, pos, out);
}

// Round 17
// 35.602 us; speedup vs baseline: 1.5772x; 1.0080x over previous
//
#include <hip/hip_runtime.h>
#include <hip/hip_bf16.h>

// NT-Xent (SimCLR) loss: B=4096, D=128, N=8192, TEMP=0.5.
// Round 17 (= round 15 resubmit; rounds 15/16 hit container-infra failures):
// r14 structure EXACTLY, one change: zn stored pre-scaled by sqrt(2*log2(e))
// so MFMA acc is already in the exp2 domain -> epilogue e = exp2f(acc)
// (kills the 33.5M-element K_E multiply; targets the measured VALU-bound
// epilogue, r10: VALUBusy 54.8%).
// Identities: acc = K_E*dot(zhat_i,zhat_j); pos = cr_scaled*ln2
// (2/K_E == ln2 exactly); diag = scaled bf16 self-dot, finalize subtracts
// exp2(diag). Same single zn buffer, same registers, same geometry as r14.

typedef short bfrag __attribute__((ext_vector_type(8)));   // 8 bf16 (4 VGPRs)
typedef float f32x4 __attribute__((ext_vector_type(4)));

static __device__ __forceinline__ unsigned short f2bf_rne(float x) {
    unsigned u = __float_as_uint(x);
    return (unsigned short)((u + 0x7fffu + ((u >> 16) & 1u)) >> 16);
}
static __device__ __forceinline__ float bf2f(unsigned short b) {
    return __uint_as_float(((unsigned)b) << 16);
}

// ------ kernel 1: normalize pair (i, i+B); emit zn = bf16(K_SQ * zhat);
// diag = scaled self-dot; pos = scaled cross-dot * ln2; zero sumexp.
__global__ __launch_bounds__(256) void nt_norm_pair(
        const float* __restrict__ zi, const float* __restrict__ zj,
        unsigned short* __restrict__ zn, float* __restrict__ diag,
        float* __restrict__ pos, float* __restrict__ sumexp) {
    constexpr int B = 4096, D = 128;
    constexpr float K_SQ = 1.6986224514464937f;            // sqrt(2*log2(e))
    constexpr float LN2  = 0.6931471805599453f;            // 2 / (2*log2(e))
    const int wave = threadIdx.x >> 6, lane = threadIdx.x & 63;
    const int p = blockIdx.x * 4 + wave;                   // 0..4095
    float2 a = reinterpret_cast<const float2*>(zi + (size_t)p * D)[lane];
    float2 b = reinterpret_cast<const float2*>(zj + (size_t)p * D)[lane];
    float sa = a.x * a.x + a.y * a.y;
    float sb = b.x * b.x + b.y * b.y;
    #pragma unroll
    for (int m = 32; m; m >>= 1) { sa += __shfl_xor(sa, m); sb += __shfl_xor(sb, m); }
    float ia = K_SQ / fmaxf(sqrtf(sa), 1e-8f);             // scale folded in
    float ib = K_SQ / fmaxf(sqrtf(sb), 1e-8f);
    unsigned short a0 = f2bf_rne(a.x * ia), a1 = f2bf_rne(a.y * ia);
    unsigned short b0 = f2bf_rne(b.x * ib), b1 = f2bf_rne(b.y * ib);
    float fa0 = bf2f(a0), fa1 = bf2f(a1), fb0 = bf2f(b0), fb1 = bf2f(b1);
    float da = fa0 * fa0 + fa1 * fa1;                      // scaled self-dot = MFMA diag
    float db = fb0 * fb0 + fb1 * fb1;
    float cr = fa0 * fb0 + fa1 * fb1;                      // scaled cross-dot
    #pragma unroll
    for (int m = 32; m; m >>= 1) {
        da += __shfl_xor(da, m); db += __shfl_xor(db, m); cr += __shfl_xor(cr, m);
    }
    reinterpret_cast<unsigned*>(zn + (size_t)p * D)[lane] =
        (unsigned)a0 | ((unsigned)a1 << 16);
    reinterpret_cast<unsigned*>(zn + (size_t)(p + B) * D)[lane] =
        (unsigned)b0 | ((unsigned)b1 << 16);
    if (lane == 0) {
        diag[p] = da; diag[p + B] = db;
        pos[p] = cr * LN2; pos[p + B] = cr * LN2;          // = 2*dot(zhat_i,zhat_j)
        sumexp[p] = 0.f; sumexp[p + B] = 0.f;              // replaces hipMemsetAsync
    }
}

// ------ kernel 2: strip-mined symmetric gram, single-barrier pipeline ------
// grid (128, 17): cached tile c = blockIdx.x; y<16: streamed tiles at
// d = 4y+t (t=0..3); y==16 (c<64 only): single tile d=64. Each unordered
// tile pair exactly once. acc[fj][fi] = K_E * sim_halfdomain (exp2-ready).
__global__ __launch_bounds__(256, 4) void nt_gram_sym(
        const unsigned short* __restrict__ zn, float* __restrict__ sumexp) {
    const int c = blockIdx.x;
    const int y = blockIdx.y;
    if (y == 16 && c >= 64) return;
    const int T  = (y == 16) ? 1 : 4;
    const int d0 = (y == 16) ? 64 : 4 * y;

    __shared__ short buf[2][64][128];                      // 2 x 16 KB stream buffers

    const short* zs = (const short*)zn;
    const int tid = threadIdx.x, wid = tid >> 6, lane = tid & 63;
    const int wj = wid >> 1, wi = wid & 1;                 // wave quadrant
    const int lr = lane & 15, lk = lane >> 4;

    // stage streamed tile t into buf[slot]: 1024 x 16B chunks, 4 per thread.
    // LDS linear; global source pre-swizzled: LDS (r, cpos) holds chunk cpos^(r&7).
    auto STAGE = [&](int t, int slot) {
        const int srow = ((c + d0 + t) & 127) * 64;
        #pragma unroll
        for (int q = 0; q < 4; ++q) {
            const int cbase = q * 256 + wid * 64;          // wave-uniform
            const int chunk = cbase + lane;                // 0..1023
            const int r = chunk >> 4;
            const int cpos = chunk & 15;
            const int csrc = cpos ^ (r & 7);
            const short* g = zs + (size_t)(srow + r) * 128 + csrc * 8;
            __builtin_amdgcn_global_load_lds(
                (const __attribute__((address_space(1))) void*)g,
                (__attribute__((address_space(3))) void*)(
                    &buf[slot][0][0] + (size_t)cbase * 8),
                16, 0, 0);
        }
    };

    STAGE(0, 0);                                           // earliest possible issue

    // cached A-frags (tile c, this wave's 32 j-rows), direct from L2 --
    // issued after STAGE(0) so the t==0 vmcnt(0) drains both together.
    bfrag ca[4][2];
    {
        const int rbase = c * 64 + wj * 32;
        #pragma unroll
        for (int ks = 0; ks < 4; ++ks)
            #pragma unroll
            for (int f = 0; f < 2; ++f)
                ca[ks][f] = *reinterpret_cast<const bfrag*>(
                    zs + (size_t)(rbase + f * 16 + lr) * 128 + ks * 32 + lk * 8);
    }

    float jp[8] = {0.f, 0.f, 0.f, 0.f, 0.f, 0.f, 0.f, 0.f};

    for (int t = 0; t < T; ++t) {
        // wait: stage(t) complete for THIS wave. t==0 also drains ca.
        // t>=1: queue oldest->newest = [atomics(t-2)]2 [stage(t)]4
        // [atomics(t-1)]2 -> vmcnt(2) leaves only the 2 newest atomics.
        if (t == 0) asm volatile("s_waitcnt vmcnt(0)" ::: "memory");
        else        asm volatile("s_waitcnt vmcnt(2)" ::: "memory");
        // single barrier: all waves have stage(t) visible AND finished
        // computing tile t-1 -> safe to overwrite buf[(t+1)&1] below.
        __builtin_amdgcn_s_barrier();
        if (t + 1 < T) STAGE(t + 1, (t + 1) & 1);          // hides under compute(t)

        // ---- compute tile t from buf[t&1] ----
        const int sb = ((c + d0 + t) & 127) * 64;          // streamed base row (i side)
        f32x4 acc[2][2] = {};                              // [fj][fi]
        #pragma unroll
        for (int ks = 0; ks < 4; ++ks) {
            bfrag cb[2];
            #pragma unroll
            for (int f = 0; f < 2; ++f) {
                const int r = wi * 32 + f * 16 + lr;
                const int cc = (ks * 4 + lk) ^ (lr & 7);   // swizzled chunk index
                cb[f] = *reinterpret_cast<const bfrag*>(&buf[t & 1][r][cc * 8]);
            }
            #pragma unroll
            for (int fj = 0; fj < 2; ++fj)
                #pragma unroll
                for (int fi = 0; fi < 2; ++fi)
                    acc[fj][fi] = __builtin_amdgcn_mfma_f32_16x16x32_bf16(
                        ca[ks][fj], cb[fi], acc[fj][fi], 0, 0, 0);
        }

        const float cw = (d0 + t) ? 1.f : 0.f;             // self-tile: no col weight
        #pragma unroll
        for (int fi = 0; fi < 2; ++fi) {
            float s = 0.f;
            #pragma unroll
            for (int fj = 0; fj < 2; ++fj)
                #pragma unroll
                for (int r = 0; r < 4; ++r) {
                    const float e = exp2f(acc[fj][fi][r]); // acc pre-scaled: no mul
                    s += e;
                    jp[fj * 4 + r] += e * cw;              // j-col partial (fma)
                }
            s += __shfl_xor(s, 16);                        // i-row sum over lk groups
            s += __shfl_xor(s, 32);
            if (lk == 0) atomicAdd(&sumexp[sb + wi * 32 + fi * 16 + lr], s);
        }
        // no trailing barrier: next iteration's leading barrier protects buf.
    }

    // ---- once per block: reduce j-col partials over 16 lr lanes ----
    float myv = 0.f;
    #pragma unroll
    for (int tt = 0; tt < 8; ++tt) {
        float v = jp[tt];
        v += __shfl_xor(v, 1);
        v += __shfl_xor(v, 2);
        v += __shfl_xor(v, 4);
        v += __shfl_xor(v, 8);
        if (lr == tt) myv = v;                             // designated writer
    }
    if (lr < 8)
        atomicAdd(&sumexp[c * 64 + wj * 32 + (lr >> 2) * 16 + lk * 4 + (lr & 3)], myv);
}

// ------ kernel 3: finalize scalar ------------------------------------------
__global__ __launch_bounds__(1024) void nt_finalize(
        const float* __restrict__ sumexp, const float* __restrict__ diag,
        const float* __restrict__ pos, float* __restrict__ out) {
    constexpr int N = 8192;
    float s = 0.f;
    for (int i = threadIdx.x; i < N; i += 1024)
        s += __logf(sumexp[i] - exp2f(diag[i])) - pos[i];  // diag pre-scaled
    #pragma unroll
    for (int m = 32; m; m >>= 1) s += __shfl_xor(s, m);
    __shared__ float red[16];
    if ((threadIdx.x & 63) == 0) red[threadIdx.x >> 6] = s;
    __syncthreads();
    if (threadIdx.x == 0) {
        float t = 0.f;
        #pragma unroll
        for (int w = 0; w < 16; ++w) t += red[w];
        out[0] = t * (1.0f / (float)N);
    }
}

extern "C" void kernel_launch(void* const* d_in, const int* in_sizes, int n_in,
                              void* d_out, int out_size, void* d_ws, size_t ws_size,
                              hipStream_t stream) {
    const float* zi = (const float*)d_in[0];
    const float* zj = (const float*)d_in[1];
    float* out = (float*)d_out;

    char* ws = (char*)d_ws;
    unsigned short* zn = (unsigned short*)ws;                    // 2 MB
    float* sumexp = (float*)(ws + 2 * 1024 * 1024);              // 32 KB
    float* diag   = (float*)(ws + 2 * 1024 * 1024 + 1 * 32768);  // 32 KB
    float* pos    = (float*)(ws + 2 * 1024 * 1024 + 2 * 32768);  // 32 KB

    nt_norm_pair<<<1024, 256, 0, stream>>>(zi, zj, zn, diag, pos, sumexp);
    nt_gram_sym<<<dim3(128, 17), 256, 0, stream>>>(zn, sumexp);
    nt_finalize<<<1, 1024, 0, stream>>>(sumexp, diag, pos, out);
}

// Round 18
// 33.744 us; speedup vs baseline: 1.6640x; 1.0551x over previous
//
#include <hip/hip_runtime.h>
#include <hip/hip_bf16.h>

// NT-Xent (SimCLR) loss: B=4096, D=128, N=8192, TEMP=0.5.
// Round 18: r17 EXACTLY (pre-scaled zn, single-barrier pipeline), one change:
// strip length T=4 -> T=8 (grid (128,9), 1088 active blocks). Halves the
// per-block serial prologue (stage0 + ca-load vmcnt(0) drain = exposed L2
// latency) and the once-per-block 32-shfl j-reduce. This isolates the T=8
// lever that r7 bundled with the refuted fused-finalize.

typedef short bfrag __attribute__((ext_vector_type(8)));   // 8 bf16 (4 VGPRs)
typedef float f32x4 __attribute__((ext_vector_type(4)));

static __device__ __forceinline__ unsigned short f2bf_rne(float x) {
    unsigned u = __float_as_uint(x);
    return (unsigned short)((u + 0x7fffu + ((u >> 16) & 1u)) >> 16);
}
static __device__ __forceinline__ float bf2f(unsigned short b) {
    return __uint_as_float(((unsigned)b) << 16);
}

// ------ kernel 1: normalize pair (i, i+B); emit zn = bf16(K_SQ * zhat);
// diag = scaled self-dot; pos = scaled cross-dot * ln2; zero sumexp.
__global__ __launch_bounds__(256) void nt_norm_pair(
        const float* __restrict__ zi, const float* __restrict__ zj,
        unsigned short* __restrict__ zn, float* __restrict__ diag,
        float* __restrict__ pos, float* __restrict__ sumexp) {
    constexpr int B = 4096, D = 128;
    constexpr float K_SQ = 1.6986224514464937f;            // sqrt(2*log2(e))
    constexpr float LN2  = 0.6931471805599453f;            // 2 / (2*log2(e))
    const int wave = threadIdx.x >> 6, lane = threadIdx.x & 63;
    const int p = blockIdx.x * 4 + wave;                   // 0..4095
    float2 a = reinterpret_cast<const float2*>(zi + (size_t)p * D)[lane];
    float2 b = reinterpret_cast<const float2*>(zj + (size_t)p * D)[lane];
    float sa = a.x * a.x + a.y * a.y;
    float sb = b.x * b.x + b.y * b.y;
    #pragma unroll
    for (int m = 32; m; m >>= 1) { sa += __shfl_xor(sa, m); sb += __shfl_xor(sb, m); }
    float ia = K_SQ / fmaxf(sqrtf(sa), 1e-8f);             // scale folded in
    float ib = K_SQ / fmaxf(sqrtf(sb), 1e-8f);
    unsigned short a0 = f2bf_rne(a.x * ia), a1 = f2bf_rne(a.y * ia);
    unsigned short b0 = f2bf_rne(b.x * ib), b1 = f2bf_rne(b.y * ib);
    float fa0 = bf2f(a0), fa1 = bf2f(a1), fb0 = bf2f(b0), fb1 = bf2f(b1);
    float da = fa0 * fa0 + fa1 * fa1;                      // scaled self-dot = MFMA diag
    float db = fb0 * fb0 + fb1 * fb1;
    float cr = fa0 * fb0 + fa1 * fb1;                      // scaled cross-dot
    #pragma unroll
    for (int m = 32; m; m >>= 1) {
        da += __shfl_xor(da, m); db += __shfl_xor(db, m); cr += __shfl_xor(cr, m);
    }
    reinterpret_cast<unsigned*>(zn + (size_t)p * D)[lane] =
        (unsigned)a0 | ((unsigned)a1 << 16);
    reinterpret_cast<unsigned*>(zn + (size_t)(p + B) * D)[lane] =
        (unsigned)b0 | ((unsigned)b1 << 16);
    if (lane == 0) {
        diag[p] = da; diag[p + B] = db;
        pos[p] = cr * LN2; pos[p + B] = cr * LN2;          // = 2*dot(zhat_i,zhat_j)
        sumexp[p] = 0.f; sumexp[p + B] = 0.f;              // replaces hipMemsetAsync
    }
}

// ------ kernel 2: strip-mined symmetric gram, single-barrier pipeline ------
// grid (128, 9): cached tile c = blockIdx.x; y<8: T=8 streamed tiles at
// d = 8y+t (t=0..7); y==8 (c<64 only): single tile d=64. Each unordered
// tile pair exactly once (8256). acc = K_E * sim (exp2-ready, pre-scaled zn).
__global__ __launch_bounds__(256, 4) void nt_gram_sym(
        const unsigned short* __restrict__ zn, float* __restrict__ sumexp) {
    const int c = blockIdx.x;
    const int y = blockIdx.y;
    if (y == 8 && c >= 64) return;
    const int T  = (y == 8) ? 1 : 8;
    const int d0 = (y == 8) ? 64 : 8 * y;

    __shared__ short buf[2][64][128];                      // 2 x 16 KB stream buffers

    const short* zs = (const short*)zn;
    const int tid = threadIdx.x, wid = tid >> 6, lane = tid & 63;
    const int wj = wid >> 1, wi = wid & 1;                 // wave quadrant
    const int lr = lane & 15, lk = lane >> 4;

    // stage streamed tile t into buf[slot]: 1024 x 16B chunks, 4 per thread.
    // LDS linear; global source pre-swizzled: LDS (r, cpos) holds chunk cpos^(r&7).
    auto STAGE = [&](int t, int slot) {
        const int srow = ((c + d0 + t) & 127) * 64;
        #pragma unroll
        for (int q = 0; q < 4; ++q) {
            const int cbase = q * 256 + wid * 64;          // wave-uniform
            const int chunk = cbase + lane;                // 0..1023
            const int r = chunk >> 4;
            const int cpos = chunk & 15;
            const int csrc = cpos ^ (r & 7);
            const short* g = zs + (size_t)(srow + r) * 128 + csrc * 8;
            __builtin_amdgcn_global_load_lds(
                (const __attribute__((address_space(1))) void*)g,
                (__attribute__((address_space(3))) void*)(
                    &buf[slot][0][0] + (size_t)cbase * 8),
                16, 0, 0);
        }
    };

    STAGE(0, 0);                                           // earliest possible issue

    // cached A-frags (tile c, this wave's 32 j-rows), direct from L2 --
    // issued after STAGE(0) so the t==0 vmcnt(0) drains both together.
    bfrag ca[4][2];
    {
        const int rbase = c * 64 + wj * 32;
        #pragma unroll
        for (int ks = 0; ks < 4; ++ks)
            #pragma unroll
            for (int f = 0; f < 2; ++f)
                ca[ks][f] = *reinterpret_cast<const bfrag*>(
                    zs + (size_t)(rbase + f * 16 + lr) * 128 + ks * 32 + lk * 8);
    }

    float jp[8] = {0.f, 0.f, 0.f, 0.f, 0.f, 0.f, 0.f, 0.f};

    for (int t = 0; t < T; ++t) {
        // wait: stage(t) complete for THIS wave. t==0 also drains ca.
        // t>=1: queue oldest->newest = [atomics(t-2)]2 [stage(t)]4
        // [atomics(t-1)]2 -> vmcnt(2) leaves only the 2 newest atomics.
        if (t == 0) asm volatile("s_waitcnt vmcnt(0)" ::: "memory");
        else        asm volatile("s_waitcnt vmcnt(2)" ::: "memory");
        // single barrier: all waves have stage(t) visible AND finished
        // computing tile t-1 -> safe to overwrite buf[(t+1)&1] below.
        __builtin_amdgcn_s_barrier();
        if (t + 1 < T) STAGE(t + 1, (t + 1) & 1);          // hides under compute(t)

        // ---- compute tile t from buf[t&1] ----
        const int sb = ((c + d0 + t) & 127) * 64;          // streamed base row (i side)
        f32x4 acc[2][2] = {};                              // [fj][fi]
        #pragma unroll
        for (int ks = 0; ks < 4; ++ks) {
            bfrag cb[2];
            #pragma unroll
            for (int f = 0; f < 2; ++f) {
                const int r = wi * 32 + f * 16 + lr;
                const int cc = (ks * 4 + lk) ^ (lr & 7);   // swizzled chunk index
                cb[f] = *reinterpret_cast<const bfrag*>(&buf[t & 1][r][cc * 8]);
            }
            #pragma unroll
            for (int fj = 0; fj < 2; ++fj)
                #pragma unroll
                for (int fi = 0; fi < 2; ++fi)
                    acc[fj][fi] = __builtin_amdgcn_mfma_f32_16x16x32_bf16(
                        ca[ks][fj], cb[fi], acc[fj][fi], 0, 0, 0);
        }

        const float cw = (d0 + t) ? 1.f : 0.f;             // self-tile: no col weight
        #pragma unroll
        for (int fi = 0; fi < 2; ++fi) {
            float s = 0.f;
            #pragma unroll
            for (int fj = 0; fj < 2; ++fj)
                #pragma unroll
                for (int r = 0; r < 4; ++r) {
                    const float e = exp2f(acc[fj][fi][r]); // acc pre-scaled: no mul
                    s += e;
                    jp[fj * 4 + r] += e * cw;              // j-col partial (fma)
                }
            s += __shfl_xor(s, 16);                        // i-row sum over lk groups
            s += __shfl_xor(s, 32);
            if (lk == 0) atomicAdd(&sumexp[sb + wi * 32 + fi * 16 + lr], s);
        }
        // no trailing barrier: next iteration's leading barrier protects buf.
    }

    // ---- once per block: reduce j-col partials over 16 lr lanes ----
    float myv = 0.f;
    #pragma unroll
    for (int tt = 0; tt < 8; ++tt) {
        float v = jp[tt];
        v += __shfl_xor(v, 1);
        v += __shfl_xor(v, 2);
        v += __shfl_xor(v, 4);
        v += __shfl_xor(v, 8);
        if (lr == tt) myv = v;                             // designated writer
    }
    if (lr < 8)
        atomicAdd(&sumexp[c * 64 + wj * 32 + (lr >> 2) * 16 + lk * 4 + (lr & 3)], myv);
}

// ------ kernel 3: finalize scalar ------------------------------------------
__global__ __launch_bounds__(1024) void nt_finalize(
        const float* __restrict__ sumexp, const float* __restrict__ diag,
        const float* __restrict__ pos, float* __restrict__ out) {
    constexpr int N = 8192;
    float s = 0.f;
    for (int i = threadIdx.x; i < N; i += 1024)
        s += __logf(sumexp[i] - exp2f(diag[i])) - pos[i];  // diag pre-scaled
    #pragma unroll
    for (int m = 32; m; m >>= 1) s += __shfl_xor(s, m);
    __shared__ float red[16];
    if ((threadIdx.x & 63) == 0) red[threadIdx.x >> 6] = s;
    __syncthreads();
    if (threadIdx.x == 0) {
        float t = 0.f;
        #pragma unroll
        for (int w = 0; w < 16; ++w) t += red[w];
        out[0] = t * (1.0f / (float)N);
    }
}

extern "C" void kernel_launch(void* const* d_in, const int* in_sizes, int n_in,
                              void* d_out, int out_size, void* d_ws, size_t ws_size,
                              hipStream_t stream) {
    const float* zi = (const float*)d_in[0];
    const float* zj = (const float*)d_in[1];
    float* out = (float*)d_out;

    char* ws = (char*)d_ws;
    unsigned short* zn = (unsigned short*)ws;                    // 2 MB
    float* sumexp = (float*)(ws + 2 * 1024 * 1024);              // 32 KB
    float* diag   = (float*)(ws + 2 * 1024 * 1024 + 1 * 32768);  // 32 KB
    float* pos    = (float*)(ws + 2 * 1024 * 1024 + 2 * 32768);  // 32 KB

    nt_norm_pair<<<1024, 256, 0, stream>>>(zi, zj, zn, diag, pos, sumexp);
    nt_gram_sym<<<dim3(128, 9), 256, 0, stream>>>(zn, sumexp);
    nt_finalize<<<1, 1024, 0, stream>>>(sumexp, diag, pos, out);
}

// Round 19
// 33.555 us; speedup vs baseline: 1.6734x; 1.0056x over previous
//
#include <hip/hip_runtime.h>
#include <hip/hip_bf16.h>

// NT-Xent (SimCLR) loss: B=4096, D=128, N=8192, TEMP=0.5.
// Round 19: r18 EXACTLY, one change: tail fold. d=64 moves from 64 stub
// blocks (y==8, T=1, full prologue each) into the y=0 strip (T=9 for c<64).
// Grid (128,8) = 1024 active blocks = exactly 4 blocks/CU x 256 CUs.

typedef short bfrag __attribute__((ext_vector_type(8)));   // 8 bf16 (4 VGPRs)
typedef float f32x4 __attribute__((ext_vector_type(4)));

static __device__ __forceinline__ unsigned short f2bf_rne(float x) {
    unsigned u = __float_as_uint(x);
    return (unsigned short)((u + 0x7fffu + ((u >> 16) & 1u)) >> 16);
}
static __device__ __forceinline__ float bf2f(unsigned short b) {
    return __uint_as_float(((unsigned)b) << 16);
}

// ------ kernel 1: normalize pair (i, i+B); emit zn = bf16(K_SQ * zhat);
// diag = scaled self-dot; pos = scaled cross-dot * ln2; zero sumexp.
__global__ __launch_bounds__(256) void nt_norm_pair(
        const float* __restrict__ zi, const float* __restrict__ zj,
        unsigned short* __restrict__ zn, float* __restrict__ diag,
        float* __restrict__ pos, float* __restrict__ sumexp) {
    constexpr int B = 4096, D = 128;
    constexpr float K_SQ = 1.6986224514464937f;            // sqrt(2*log2(e))
    constexpr float LN2  = 0.6931471805599453f;            // 2 / (2*log2(e))
    const int wave = threadIdx.x >> 6, lane = threadIdx.x & 63;
    const int p = blockIdx.x * 4 + wave;                   // 0..4095
    float2 a = reinterpret_cast<const float2*>(zi + (size_t)p * D)[lane];
    float2 b = reinterpret_cast<const float2*>(zj + (size_t)p * D)[lane];
    float sa = a.x * a.x + a.y * a.y;
    float sb = b.x * b.x + b.y * b.y;
    #pragma unroll
    for (int m = 32; m; m >>= 1) { sa += __shfl_xor(sa, m); sb += __shfl_xor(sb, m); }
    float ia = K_SQ / fmaxf(sqrtf(sa), 1e-8f);             // scale folded in
    float ib = K_SQ / fmaxf(sqrtf(sb), 1e-8f);
    unsigned short a0 = f2bf_rne(a.x * ia), a1 = f2bf_rne(a.y * ia);
    unsigned short b0 = f2bf_rne(b.x * ib), b1 = f2bf_rne(b.y * ib);
    float fa0 = bf2f(a0), fa1 = bf2f(a1), fb0 = bf2f(b0), fb1 = bf2f(b1);
    float da = fa0 * fa0 + fa1 * fa1;                      // scaled self-dot = MFMA diag
    float db = fb0 * fb0 + fb1 * fb1;
    float cr = fa0 * fb0 + fa1 * fb1;                      // scaled cross-dot
    #pragma unroll
    for (int m = 32; m; m >>= 1) {
        da += __shfl_xor(da, m); db += __shfl_xor(db, m); cr += __shfl_xor(cr, m);
    }
    reinterpret_cast<unsigned*>(zn + (size_t)p * D)[lane] =
        (unsigned)a0 | ((unsigned)a1 << 16);
    reinterpret_cast<unsigned*>(zn + (size_t)(p + B) * D)[lane] =
        (unsigned)b0 | ((unsigned)b1 << 16);
    if (lane == 0) {
        diag[p] = da; diag[p + B] = db;
        pos[p] = cr * LN2; pos[p + B] = cr * LN2;          // = 2*dot(zhat_i,zhat_j)
        sumexp[p] = 0.f; sumexp[p + B] = 0.f;              // replaces hipMemsetAsync
    }
}

// ------ kernel 2: strip-mined symmetric gram, single-barrier pipeline ------
// grid (128, 8): cached tile c = blockIdx.x; strip d = 8y+t (t=0..7);
// y==0 && c<64 additionally appends d=64 (T=9). Each unordered tile pair
// exactly once (8256). acc = K_E * sim (exp2-ready, pre-scaled zn).
__global__ __launch_bounds__(256, 4) void nt_gram_sym(
        const unsigned short* __restrict__ zn, float* __restrict__ sumexp) {
    const int c = blockIdx.x;
    const int y = blockIdx.y;
    const int T  = (y == 0 && c < 64) ? 9 : 8;
    const int d0 = 8 * y;

    __shared__ short buf[2][64][128];                      // 2 x 16 KB stream buffers

    const short* zs = (const short*)zn;
    const int tid = threadIdx.x, wid = tid >> 6, lane = tid & 63;
    const int wj = wid >> 1, wi = wid & 1;                 // wave quadrant
    const int lr = lane & 15, lk = lane >> 4;

    // stage streamed tile t into buf[slot]: 1024 x 16B chunks, 4 per thread.
    // LDS linear; global source pre-swizzled: LDS (r, cpos) holds chunk cpos^(r&7).
    // t==8 (only y==0, c<64) maps to d=64.
    auto STAGE = [&](int t, int slot) {
        const int d = (t == 8) ? 64 : d0 + t;
        const int srow = ((c + d) & 127) * 64;
        #pragma unroll
        for (int q = 0; q < 4; ++q) {
            const int cbase = q * 256 + wid * 64;          // wave-uniform
            const int chunk = cbase + lane;                // 0..1023
            const int r = chunk >> 4;
            const int cpos = chunk & 15;
            const int csrc = cpos ^ (r & 7);
            const short* g = zs + (size_t)(srow + r) * 128 + csrc * 8;
            __builtin_amdgcn_global_load_lds(
                (const __attribute__((address_space(1))) void*)g,
                (__attribute__((address_space(3))) void*)(
                    &buf[slot][0][0] + (size_t)cbase * 8),
                16, 0, 0);
        }
    };

    STAGE(0, 0);                                           // earliest possible issue

    // cached A-frags (tile c, this wave's 32 j-rows), direct from L2 --
    // issued after STAGE(0) so the t==0 vmcnt(0) drains both together.
    bfrag ca[4][2];
    {
        const int rbase = c * 64 + wj * 32;
        #pragma unroll
        for (int ks = 0; ks < 4; ++ks)
            #pragma unroll
            for (int f = 0; f < 2; ++f)
                ca[ks][f] = *reinterpret_cast<const bfrag*>(
                    zs + (size_t)(rbase + f * 16 + lr) * 128 + ks * 32 + lk * 8);
    }

    float jp[8] = {0.f, 0.f, 0.f, 0.f, 0.f, 0.f, 0.f, 0.f};

    for (int t = 0; t < T; ++t) {
        // wait: stage(t) complete for THIS wave. t==0 also drains ca.
        // t>=1: queue oldest->newest = [atomics(t-2)]2 [stage(t)]4
        // [atomics(t-1)]2 -> vmcnt(2) leaves only the 2 newest atomics.
        if (t == 0) asm volatile("s_waitcnt vmcnt(0)" ::: "memory");
        else        asm volatile("s_waitcnt vmcnt(2)" ::: "memory");
        // single barrier: all waves have stage(t) visible AND finished
        // computing tile t-1 -> safe to overwrite buf[(t+1)&1] below.
        __builtin_amdgcn_s_barrier();
        if (t + 1 < T) STAGE(t + 1, (t + 1) & 1);          // hides under compute(t)

        // ---- compute tile t from buf[t&1] ----
        const int d = (t == 8) ? 64 : d0 + t;
        const int sb = ((c + d) & 127) * 64;               // streamed base row (i side)
        f32x4 acc[2][2] = {};                              // [fj][fi]
        #pragma unroll
        for (int ks = 0; ks < 4; ++ks) {
            bfrag cb[2];
            #pragma unroll
            for (int f = 0; f < 2; ++f) {
                const int r = wi * 32 + f * 16 + lr;
                const int cc = (ks * 4 + lk) ^ (lr & 7);   // swizzled chunk index
                cb[f] = *reinterpret_cast<const bfrag*>(&buf[t & 1][r][cc * 8]);
            }
            #pragma unroll
            for (int fj = 0; fj < 2; ++fj)
                #pragma unroll
                for (int fi = 0; fi < 2; ++fi)
                    acc[fj][fi] = __builtin_amdgcn_mfma_f32_16x16x32_bf16(
                        ca[ks][fj], cb[fi], acc[fj][fi], 0, 0, 0);
        }

        const float cw = d ? 1.f : 0.f;                    // self-tile: no col weight
        #pragma unroll
        for (int fi = 0; fi < 2; ++fi) {
            float s = 0.f;
            #pragma unroll
            for (int fj = 0; fj < 2; ++fj)
                #pragma unroll
                for (int r = 0; r < 4; ++r) {
                    const float e = exp2f(acc[fj][fi][r]); // acc pre-scaled: no mul
                    s += e;
                    jp[fj * 4 + r] += e * cw;              // j-col partial (fma)
                }
            s += __shfl_xor(s, 16);                        // i-row sum over lk groups
            s += __shfl_xor(s, 32);
            if (lk == 0) atomicAdd(&sumexp[sb + wi * 32 + fi * 16 + lr], s);
        }
        // no trailing barrier: next iteration's leading barrier protects buf.
    }

    // ---- once per block: reduce j-col partials over 16 lr lanes ----
    float myv = 0.f;
    #pragma unroll
    for (int tt = 0; tt < 8; ++tt) {
        float v = jp[tt];
        v += __shfl_xor(v, 1);
        v += __shfl_xor(v, 2);
        v += __shfl_xor(v, 4);
        v += __shfl_xor(v, 8);
        if (lr == tt) myv = v;                             // designated writer
    }
    if (lr < 8)
        atomicAdd(&sumexp[c * 64 + wj * 32 + (lr >> 2) * 16 + lk * 4 + (lr & 3)], myv);
}

// ------ kernel 3: finalize scalar ------------------------------------------
__global__ __launch_bounds__(1024) void nt_finalize(
        const float* __restrict__ sumexp, const float* __restrict__ diag,
        const float* __restrict__ pos, float* __restrict__ out) {
    constexpr int N = 8192;
    float s = 0.f;
    for (int i = threadIdx.x; i < N; i += 1024)
        s += __logf(sumexp[i] - exp2f(diag[i])) - pos[i];  // diag pre-scaled
    #pragma unroll
    for (int m = 32; m; m >>= 1) s += __shfl_xor(s, m);
    __shared__ float red[16];
    if ((threadIdx.x & 63) == 0) red[threadIdx.x >> 6] = s;
    __syncthreads();
    if (threadIdx.x == 0) {
        float t = 0.f;
        #pragma unroll
        for (int w = 0; w < 16; ++w) t += red[w];
        out[0] = t * (1.0f / (float)N);
    }
}

extern "C" void kernel_launch(void* const* d_in, const int* in_sizes, int n_in,
                              void* d_out, int out_size, void* d_ws, size_t ws_size,
                              hipStream_t stream) {
    const float* zi = (const float*)d_in[0];
    const float* zj = (const float*)d_in[1];
    float* out = (float*)d_out;

    char* ws = (char*)d_ws;
    unsigned short* zn = (unsigned short*)ws;                    // 2 MB
    float* sumexp = (float*)(ws + 2 * 1024 * 1024);              // 32 KB
    float* diag   = (float*)(ws + 2 * 1024 * 1024 + 1 * 32768);  // 32 KB
    float* pos    = (float*)(ws + 2 * 1024 * 1024 + 2 * 32768);  // 32 KB

    nt_norm_pair<<<1024, 256, 0, stream>>>(zi, zj, zn, diag, pos, sumexp);
    nt_gram_sym<<<dim3(128, 8), 256, 0, stream>>>(zn, sumexp);
    nt_finalize<<<1, 1024, 0, stream>>>(sumexp, diag, pos, out);
}